// Round 9
// baseline (188.835 us; speedup 1.0000x reference)
//
#include <hip/hip_runtime.h>

#define IMG_W 512
#define IMG_H 512
#define NPLANES 48         // 16 * 3
#define NPIX 12582912.0    // 16*3*512*512
#define SB 72              // bf16 column stride: rows 0..63 used (42..63 zero pad)
#define FSB (32 * SB)      // ushorts per field = 2304
#define NBLOCKS (16*16*48) // 12288

typedef __attribute__((ext_vector_type(8))) short bf16x8;
typedef __attribute__((ext_vector_type(4))) float f32x4;

static __device__ inline unsigned short f2bf(float v) {
    union { float f; unsigned int u; } x; x.f = v;
    unsigned int r = x.u + 0x7FFFu + ((x.u >> 16) & 1u);   // RNE
    return (unsigned short)(r >> 16);
}

// Horizontal pass: scalar (R8-proven), writes bf16 h-fields to LDS,
//   layout idx(f,c,r) = f*FSB + c*SB + r, r in 0..63 (42..63 zeroed).
// Vertical pass: banded MFMA per field: Out(32x32) = Wband(32x42) . H(42x32).
//   Wave wid -> out quadrant (R=wid>>1, C=wid&1). R=0 needs only K-block 0
//   (weights for m>=32 vanish); R=1 needs both K-blocks.
// Epilogue is pointwise across the 5 identical-layout D-frags + global sum,
// so fragment-layout permutations cancel.

__global__ __launch_bounds__(256) void ssim_fused_kernel(
    const float* __restrict__ pred,
    const float* __restrict__ label,
    float* __restrict__ partial)
{
    __shared__ unsigned short hB[5 * FSB];   // 23040 B -> 6 blocks/CU

    const int tid = threadIdx.x;
    const int ox = blockIdx.x * 32;
    const int oy = blockIdx.y * 32;
    const int plane = blockIdx.z;
    const float* __restrict__ xp = pred  + (size_t)plane * (IMG_W * IMG_H);
    const float* __restrict__ yp = label + (size_t)plane * (IMG_W * IMG_H);

    // Gaussian weights (sigma=1.5, K=11), normalized — registers (R8-proven).
    float w[11];
    {
        float s = 0.f;
        #pragma unroll
        for (int i = 0; i < 11; ++i) {
            float d = (float)(i - 5);
            w[i] = expf(-d * d / 4.5f);
            s += w[i];
        }
        float inv = 1.0f / s;
        #pragma unroll
        for (int i = 0; i < 11; ++i) w[i] *= inv;
    }

    // ---- Horizontal pass: 64 rows x 8 groups of 4 cols = 512 tasks (2/thr).
    // Rows 0..41 are real ext rows; 42..63 write zeros (K-pad, NaN guard).
    const bool xInterior = (blockIdx.x != 0) && (blockIdx.x != (IMG_W / 32 - 1));
    for (int i = tid; i < 512; i += 256) {
        int r  = i >> 3;          // ext row 0..63
        int g  = i & 7;           // col group 0..7
        int wb = (g * 4) * SB + r;
        if (r < 42) {
            int gy = oy - 5 + r;
            int c0 = ox + g * 4;

            float bx_[24], by_[24];
            bool rowok = ((unsigned)gy < (unsigned)IMG_H);
            if (!rowok) {
                #pragma unroll
                for (int j = 0; j < 24; ++j) { bx_[j] = 0.f; by_[j] = 0.f; }
            } else if (xInterior) {
                const float4* px4 = reinterpret_cast<const float4*>(xp + gy * IMG_W + (c0 - 8));
                const float4* py4 = reinterpret_cast<const float4*>(yp + gy * IMG_W + (c0 - 8));
                #pragma unroll
                for (int j = 0; j < 6; ++j) {
                    float4 a = px4[j];
                    float4 b = py4[j];
                    bx_[4*j+0] = a.x; bx_[4*j+1] = a.y; bx_[4*j+2] = a.z; bx_[4*j+3] = a.w;
                    by_[4*j+0] = b.x; by_[4*j+1] = b.y; by_[4*j+2] = b.z; by_[4*j+3] = b.w;
                }
            } else {
                #pragma unroll
                for (int j = 0; j < 24; ++j) {
                    int col = c0 - 8 + j;
                    bool ok = ((unsigned)col < (unsigned)IMG_W);
                    bx_[j] = ok ? xp[gy * IMG_W + col] : 0.f;
                    by_[j] = ok ? yp[gy * IMG_W + col] : 0.f;
                }
            }

            float a0[4] = {0,0,0,0}, a1[4] = {0,0,0,0}, a2[4] = {0,0,0,0},
                  a3[4] = {0,0,0,0}, a4[4] = {0,0,0,0};
            // output o taps window cols j = o+3 .. o+13
            #pragma unroll
            for (int j = 3; j <= 16; ++j) {
                float xv = bx_[j], yv = by_[j];
                float xx = xv * xv, yy = yv * yv, xy = xv * yv;
                #pragma unroll
                for (int o = 0; o < 4; ++o) {
                    int k = j - 3 - o;
                    if (k >= 0 && k <= 10) {
                        float wk = w[k];
                        a0[o] += wk * xv;
                        a1[o] += wk * yv;
                        a2[o] += wk * xx;
                        a3[o] += wk * yy;
                        a4[o] += wk * xy;
                    }
                }
            }
            #pragma unroll
            for (int o = 0; o < 4; ++o) {
                hB[wb + o*SB + 0*FSB] = f2bf(a0[o]);
                hB[wb + o*SB + 1*FSB] = f2bf(a1[o]);
                hB[wb + o*SB + 2*FSB] = f2bf(a2[o]);
                hB[wb + o*SB + 3*FSB] = f2bf(a3[o]);
                hB[wb + o*SB + 4*FSB] = f2bf(a4[o]);
            }
        } else {
            #pragma unroll
            for (int o = 0; o < 4; ++o) {
                hB[wb + o*SB + 0*FSB] = 0;
                hB[wb + o*SB + 1*FSB] = 0;
                hB[wb + o*SB + 2*FSB] = 0;
                hB[wb + o*SB + 3*FSB] = 0;
                hB[wb + o*SB + 4*FSB] = 0;
            }
        }
    }
    __syncthreads();

    // ---- Vertical pass: MFMA banded matmul ----
    float lsum = 0.f;
    {
        const int lane = tid & 63;
        const int wid  = tid >> 6;
        const int R    = wid >> 1;     // out-row tile 0/1
        const int Cc   = wid & 1;      // out-col tile 0/1
        const int lrow = lane & 15;
        const int lk   = (lane >> 4) << 3;   // k-slot base 0/8/16/24

        // A-frags: Wband[row][m] = w[m - row], row = 16R + lrow.
        bf16x8 afr0, afr1;
        #pragma unroll
        for (int j = 0; j < 8; ++j) {
            int m0 = lk + j;
            int i0 = m0 - (16 * R + lrow);
            float v0 = (i0 >= 0 && i0 <= 10) ? w[i0] : 0.f;
            afr0[j] = (short)f2bf(v0);
            int m1 = m0 + 32;
            int i1 = m1 - (16 * R + lrow);
            float v1 = (i1 >= 0 && i1 <= 10) ? w[i1] : 0.f;
            afr1[j] = (short)f2bf(v1);
        }

        const int bcol = (16 * Cc + lrow) * SB + lk;   // ushort index (16B aligned)

        f32x4 acc[5];
        #pragma unroll
        for (int f = 0; f < 5; ++f) {
            f32x4 a = {0.f, 0.f, 0.f, 0.f};
            bf16x8 b0 = *reinterpret_cast<const bf16x8*>(&hB[f * FSB + bcol]);
            a = __builtin_amdgcn_mfma_f32_16x16x32_bf16(afr0, b0, a, 0, 0, 0);
            if (R == 1) {
                bf16x8 b1 = *reinterpret_cast<const bf16x8*>(&hB[f * FSB + bcol + 32]);
                a = __builtin_amdgcn_mfma_f32_16x16x32_bf16(afr1, b1, a, 0, 0, 0);
            }
            acc[f] = a;
        }

        // ---- SSIM epilogue: pointwise across the 5 D-frags ----
        #pragma unroll
        for (int i = 0; i < 4; ++i) {
            float mu1 = acc[0][i], mu2 = acc[1][i];
            float mu1s = mu1 * mu1, mu2s = mu2 * mu2, mu12 = mu1 * mu2;
            float s1  = acc[2][i] - mu1s;
            float s2  = acc[3][i] - mu2s;
            float s12 = acc[4][i] - mu12;
            const float C1 = 1e-4f, C2 = 9e-4f;
            float num = (2.f * mu12 + C1) * (2.f * s12 + C2);
            float den = (mu1s + mu2s + C1) * (s1 + s2 + C2);
            lsum += num * __builtin_amdgcn_rcpf(den);
        }
    }

    // ---- Block reduction -> one float partial per block ----
    #pragma unroll
    for (int off = 32; off > 0; off >>= 1)
        lsum += __shfl_down(lsum, off, 64);

    __shared__ float wsum[4];
    if ((tid & 63) == 0) wsum[tid >> 6] = lsum;
    __syncthreads();
    if (tid == 0) {
        int bid = (blockIdx.z * gridDim.y + blockIdx.y) * gridDim.x + blockIdx.x;
        partial[bid] = wsum[0] + wsum[1] + wsum[2] + wsum[3];
    }
}

__global__ __launch_bounds__(1024) void ssim_finalize_kernel(
    const float* __restrict__ partial, float* __restrict__ out)
{
    double s = 0.0;
    for (int i = threadIdx.x; i < NBLOCKS; i += 1024) s += (double)partial[i];
    #pragma unroll
    for (int off = 32; off > 0; off >>= 1) s += __shfl_down(s, off, 64);
    __shared__ double ws[16];
    if ((threadIdx.x & 63) == 0) ws[threadIdx.x >> 6] = s;
    __syncthreads();
    if (threadIdx.x == 0) {
        double t = 0.0;
        #pragma unroll
        for (int k = 0; k < 16; ++k) t += ws[k];
        out[0] = 1.0f - (float)(t * (1.0 / NPIX));
    }
}

extern "C" void kernel_launch(void* const* d_in, const int* in_sizes, int n_in,
                              void* d_out, int out_size, void* d_ws, size_t ws_size,
                              hipStream_t stream) {
    const float* pred  = (const float*)d_in[0];
    const float* label = (const float*)d_in[1];
    float* out = (float*)d_out;
    float* partial = (float*)d_ws;   // NBLOCKS floats, fully overwritten every call

    dim3 grid(IMG_W / 32, IMG_H / 32, NPLANES);
    ssim_fused_kernel<<<grid, 256, 0, stream>>>(pred, label, partial);
    ssim_finalize_kernel<<<1, 1024, 0, stream>>>(partial, out);
}